// Round 1
// 441.099 us; speedup vs baseline: 1.0287x; 1.0287x over previous
//
#include <hip/hip_runtime.h>
#include <hip/hip_fp16.h>

// Problem constants
#define B_SZ  4096
#define DIN   1024
#define DH    2048
#define K_TOT 3072      // DIN + DH
#define N_TOT 8192      // 4 * DH

// GEMM tile (256^2 8-phase-class schedule)
#define BM 256
#define BN 256          // = 64 hidden units * 4 gates, gate-blocked @64 per ntile
#define BK 64
#define NK (K_TOT / BK) // 48

typedef _Float16 half8 __attribute__((ext_vector_type(8)));
typedef float   float4v __attribute__((ext_vector_type(4)));

// ---------- async global->LDS (16B per lane, wave-uniform LDS base) ----------
__device__ __forceinline__ void load_lds16(const void* g, void* l) {
    __builtin_amdgcn_global_load_lds(
        (const __attribute__((address_space(1))) void*)g,
        (__attribute__((address_space(3))) void*)l,
        16, 0, 0);
}

// ---------- fused cast kernel: A-part + W-part in one launch ----------
// blockIdx.x < A_BLOCKS: cast x|h_prev -> A [B_SZ, K_TOT] fp16
// else:                  cast W|R -> Wb [N_TOT, K_TOT] fp16, gate-blocked @64:
//   Wb row n: ntile = n>>8; gate g = (n>>6)&3; unit j = (n>>8)*64 + (n&63)
#define A_BLOCKS ((B_SZ * K_TOT / 8) / 256)
#define W_BLOCKS ((N_TOT * K_TOT / 8) / 256)

__global__ __launch_bounds__(256) void cast_all_kernel(
        const float* __restrict__ x, const float* __restrict__ h,
        const float* __restrict__ Wz, const float* __restrict__ Wi,
        const float* __restrict__ Wf, const float* __restrict__ Wo,
        const float* __restrict__ Rz, const float* __restrict__ Ri,
        const float* __restrict__ Rf, const float* __restrict__ Ro,
        _Float16* __restrict__ A, _Float16* __restrict__ Wb) {
    const float* src;
    _Float16* dst;
    if (blockIdx.x < A_BLOCKS) {
        int idx = (blockIdx.x * 256 + threadIdx.x) * 8;
        int b = idx / K_TOT;
        int c = idx - b * K_TOT;
        src = (c < DIN) ? (x + (size_t)b * DIN + c) : (h + (size_t)b * DH + (c - DIN));
        dst = A + idx;
    } else {
        int idx = ((blockIdx.x - A_BLOCKS) * 256 + threadIdx.x) * 8;
        int n = idx / K_TOT;
        int c = idx - n * K_TOT;
        int g = (n >> 6) & 3;
        int j = ((n >> 8) << 6) | (n & 63);
        const float* W = (g == 0) ? Wz : (g == 1) ? Wi : (g == 2) ? Wf : Wo;
        const float* R = (g == 0) ? Rz : (g == 1) ? Ri : (g == 2) ? Rf : Ro;
        src = (c < DIN) ? (W + (size_t)j * DIN + c) : (R + (size_t)j * DH + (c - DIN));
        dst = Wb + idx;
    }
    float4 v0 = *reinterpret_cast<const float4*>(src);
    float4 v1 = *reinterpret_cast<const float4*>(src + 4);
    half8 o;
    o[0] = (_Float16)v0.x; o[1] = (_Float16)v0.y;
    o[2] = (_Float16)v0.z; o[3] = (_Float16)v0.w;
    o[4] = (_Float16)v1.x; o[5] = (_Float16)v1.y;
    o[6] = (_Float16)v1.z; o[7] = (_Float16)v1.w;
    *reinterpret_cast<half8*>(dst) = o;
}

// ---------- fused GEMM + sLSTM pointwise epilogue (256^2, 4-phase/K-tile) ----
// 512 threads = 8 waves (wm=wv>>2 in {0,1}, wn=wv&3 in {0..3}).
// Interleaved frag mapping: A row = mf*32 + wm*16 + l16 (mf 0..7),
//                           B col = nf*64 + wn*16 + l16 (nf 0..3 = GATE).
// => mf 0-3 touch A-half0, mf 4-7 A-half1; nf 0-1 B-half0, nf 2-3 B-half1.
// Per K-tile, 4 phases = 4 C-quadrants x K=64 (16 MFMA each):
//   P0: acc[0..3][0..1] (needs A0,B0)   | stages A0(t+1)
//   P1: acc[0..3][2..3] (needs B1)      | stages B0(t+1)
//   P2: acc[4..7][2..3] (needs A1)      | stages B1(t+1)
//   P3: acc[4..7][0..1] (regs only)     | stages A1(t+1)
// Counted vmcnt(4) at P0/P1/P2 (2 half-tiles = 4 loads stay in flight),
// raw s_barrier, setprio(1) around each 16-MFMA cluster. Never vmcnt(0)
// in the main loop.
//
// LDS swizzle (64-elem = 128B rows): 16B chunk slot s of row r holds source
// chunk s^(r&7). Staging: linear LDS dest + pre-swizzled global source
// (src k-chunk = (l&7)^((l>>3)&7), lane-constant). Frag read slot
// (kp*4+quad)^(l16&7) -> conflict-free (verified 0 in the 128^2 kernel).
__global__ __launch_bounds__(512, 2) void slstm_gemm_kernel(
        const _Float16* __restrict__ A, const _Float16* __restrict__ Wb,
        const float* __restrict__ c_prev, const float* __restrict__ n_prev,
        const float* __restrict__ bz, const float* __restrict__ bi,
        const float* __restrict__ bf, const float* __restrict__ bo,
        float* __restrict__ Hout) {
    __shared__ __align__(16) _Float16 As[2][BM * BK];   // 2 x 32 KB
    __shared__ __align__(16) _Float16 Bs[2][BN * BK];   // 2 x 32 KB

    // XCD-aware swizzle: 512 blocks, 8 XCDs -> XCD x owns mtiles {2x,2x+1}
    // (2 A-panels = 3 MB, fits 4 MB per-XCD L2; B streams via L3).
    const int bid   = blockIdx.x;                 // 0..511
    const int swz   = (bid & 7) * 64 + (bid >> 3);
    const int ntile = swz & 31;                   // 0..31
    const int mtile = swz >> 5;                   // 0..15
    const int m0 = mtile * BM;
    const int n0 = ntile * BN;

    const int tid  = threadIdx.x;
    const int wv   = tid >> 6;         // 0..7
    const int wm   = wv >> 2;          // 0..1
    const int wn   = wv & 3;           // 0..3
    const int l    = tid & 63;
    const int quad = l >> 4;
    const int l16  = l & 15;

    float4v acc[8][4];
#pragma unroll
    for (int i = 0; i < 8; i++)
#pragma unroll
        for (int j = 0; j < 4; j++) acc[i][j] = (float4v){0.f, 0.f, 0.f, 0.f};

    // ---- staging addressing ----
    const int lrow  = l >> 3;                      // 0..7
    const int skoff = ((l & 7) ^ lrow) * 8;        // pre-swizzled src k-chunk
    const _Float16* Ag = A  + (size_t)(m0 + wv * 16 + lrow) * K_TOT + skoff;
    const _Float16* Bg = Wb + (size_t)(n0 + wv * 16 + lrow) * K_TOT + skoff;
    const int ldsA = wv * 1024;                    // wave-uniform elem offset

#define STAGE_A(h, nb, kk) do { \
    load_lds16(Ag + (size_t)(h) * 128 * K_TOT + (kk),        &As[nb][(h) * 8192 + ldsA]); \
    load_lds16(Ag + ((size_t)(h) * 128 + 8) * K_TOT + (kk),  &As[nb][(h) * 8192 + ldsA + 512]); } while (0)
#define STAGE_B(h, nb, kk) do { \
    load_lds16(Bg + (size_t)(h) * 128 * K_TOT + (kk),        &Bs[nb][(h) * 8192 + ldsA]); \
    load_lds16(Bg + ((size_t)(h) * 128 + 8) * K_TOT + (kk),  &Bs[nb][(h) * 8192 + ldsA + 512]); } while (0)

    // ---- fragment read addressing ----
    const int aRowBase = wm * 16 + l16;            // + mf*32
    const int bColBase = wn * 16 + l16;            // + nf*64
    const int sl0 = ((0 + quad) ^ (l16 & 7)) * 8;  // kp=0 swizzled slot
    const int sl1 = ((4 + quad) ^ (l16 & 7)) * 8;  // kp=1

    half8 afr[4][2], bfr0[2][2], bfr1[2][2];

#define LOAD_A(MB) \
    _Pragma("unroll") \
    for (int mf = 0; mf < 4; ++mf) { \
        const _Float16* p = Ac + (size_t)(aRowBase + ((MB) + mf) * 32) * BK; \
        afr[mf][0] = *reinterpret_cast<const half8*>(p + sl0); \
        afr[mf][1] = *reinterpret_cast<const half8*>(p + sl1); \
    }
#define LOAD_B(DST, NB) \
    _Pragma("unroll") \
    for (int nf = 0; nf < 2; ++nf) { \
        const _Float16* p = Bc + (size_t)(bColBase + ((NB) + nf) * 64) * BK; \
        DST[nf][0] = *reinterpret_cast<const half8*>(p + sl0); \
        DST[nf][1] = *reinterpret_cast<const half8*>(p + sl1); \
    }
#define MFMA16(MB, NB, BF) \
    _Pragma("unroll") \
    for (int kp = 0; kp < 2; ++kp) \
    _Pragma("unroll") \
    for (int mf = 0; mf < 4; ++mf) \
    _Pragma("unroll") \
    for (int nf = 0; nf < 2; ++nf) \
        acc[(MB) + mf][(NB) + nf] = __builtin_amdgcn_mfma_f32_16x16x32_f16( \
            afr[mf][kp], BF[nf][kp], acc[(MB) + mf][(NB) + nf], 0, 0, 0);

    // ---- prologue: stage tile 0 into buf0, issue order A0,B0,B1,A1 ----
    STAGE_A(0, 0, 0);
    STAGE_B(0, 0, 0);
    STAGE_B(1, 0, 0);
    STAGE_A(1, 0, 0);

    for (int kt = 0; kt < NK; ++kt) {
        const int cur = kt & 1;
        const int nxt = cur ^ 1;
        const int kk  = (kt + 1 < NK) ? (kt + 1) * BK : 0;  // wrap: harmless re-stage
        const _Float16* Ac = &As[cur][0];
        const _Float16* Bc = &Bs[cur][0];

        // ---- Phase 0: needs A0(t),B0(t) done; B1(t),A1(t) may be in flight
        asm volatile("s_waitcnt vmcnt(4)" ::: "memory");
        __builtin_amdgcn_s_barrier();
        LOAD_A(0);
        LOAD_B(bfr0, 0);
        STAGE_A(0, nxt, kk);
        __builtin_amdgcn_s_setprio(1);
        MFMA16(0, 0, bfr0);
        __builtin_amdgcn_s_setprio(0);

        // ---- Phase 1: needs B1(t); A1(t),A0(t+1) in flight
        asm volatile("s_waitcnt vmcnt(4)" ::: "memory");
        __builtin_amdgcn_s_barrier();
        LOAD_B(bfr1, 2);
        STAGE_B(0, nxt, kk);
        __builtin_amdgcn_s_setprio(1);
        MFMA16(0, 2, bfr1);
        __builtin_amdgcn_s_setprio(0);

        // ---- Phase 2: needs A1(t); A0(t+1),B0(t+1) in flight
        asm volatile("s_waitcnt vmcnt(4)" ::: "memory");
        __builtin_amdgcn_s_barrier();
        LOAD_A(4);
        STAGE_B(1, nxt, kk);
        __builtin_amdgcn_s_setprio(1);
        MFMA16(4, 2, bfr1);
        __builtin_amdgcn_s_setprio(0);

        // ---- Phase 3: registers only (afr mf4-7 + persistent bfr0)
        __builtin_amdgcn_s_barrier();
        STAGE_A(1, nxt, kk);
        __builtin_amdgcn_s_setprio(1);
        MFMA16(4, 0, bfr0);
        __builtin_amdgcn_s_setprio(0);
    }

    // ---- Epilogue: C/D layout col=l16 (unit), row=quad*4+reg; nf = gate ----
    const int j = ntile * 64 + wn * 16 + l16;   // hidden unit, uniform over nf/mf
    const float bzv = bz[j], biv = bi[j], bfv = bf[j], bov = bo[j];
#pragma unroll
    for (int mf = 0; mf < 8; ++mf) {
#pragma unroll
        for (int r = 0; r < 4; ++r) {
            const int row = m0 + mf * 32 + wm * 16 + quad * 4 + r;
            const size_t off = (size_t)row * DH + j;
            const float az  = acc[mf][0][r] + bzv;
            const float ai  = acc[mf][1][r] + biv;
            const float af_ = acc[mf][2][r] + bfv;
            const float ao  = acc[mf][3][r] + bov;
            // tanh via exp, sign-safe (e2 <= 1 always; no inf/inf)
            const float ax = fabsf(az);
            const float e2 = __expf(-2.0f * ax);
            float tz = __fdividef(1.0f - e2, 1.0f + e2);
            tz = (az >= 0.0f) ? tz : -tz;
            const float iv = __expf(ai);
            const float fv = __expf(af_);
            const float ov = __fdividef(1.0f, 1.0f + __expf(-ao));
            const float cc = fv * c_prev[off] + iv * tz;
            const float nn = fv * n_prev[off] + iv;
            Hout[off] = ov * __fdividef(cc, nn);
        }
    }
#undef STAGE_A
#undef STAGE_B
#undef LOAD_A
#undef LOAD_B
#undef MFMA16
}

extern "C" void kernel_launch(void* const* d_in, const int* in_sizes, int n_in,
                              void* d_out, int out_size, void* d_ws, size_t ws_size,
                              hipStream_t stream) {
    const float* x      = (const float*)d_in[0];
    const float* h_prev = (const float*)d_in[1];
    const float* c_prev = (const float*)d_in[2];
    const float* n_prev = (const float*)d_in[3];
    const float* Wz = (const float*)d_in[4];
    const float* Wi = (const float*)d_in[5];
    const float* Wf = (const float*)d_in[6];
    const float* Wo = (const float*)d_in[7];
    const float* bz = (const float*)d_in[8];
    const float* bi = (const float*)d_in[9];
    const float* bf = (const float*)d_in[10];
    const float* bo = (const float*)d_in[11];
    const float* Rz = (const float*)d_in[12];
    const float* Ri = (const float*)d_in[13];
    const float* Rf = (const float*)d_in[14];
    const float* Ro = (const float*)d_in[15];

    _Float16* A  = (_Float16*)d_ws;                       // [B_SZ, K_TOT]
    _Float16* Wb = A + (size_t)B_SZ * K_TOT;              // [N_TOT, K_TOT]

    cast_all_kernel<<<A_BLOCKS + W_BLOCKS, 256, 0, stream>>>(
        x, h_prev, Wz, Wi, Wf, Wo, Rz, Ri, Rf, Ro, A, Wb);

    dim3 grid(N_TOT / BN * (B_SZ / BM));   // 32 * 16 = 512 blocks (1D, swizzled in-kernel)
    slstm_gemm_kernel<<<grid, 512, 0, stream>>>(
        A, Wb, c_prev, n_prev, bz, bi, bf, bo, (float*)d_out);
}

// Round 2
// 435.050 us; speedup vs baseline: 1.0430x; 1.0139x over previous
//
#include <hip/hip_runtime.h>
#include <hip/hip_fp16.h>

// Problem constants
#define B_SZ  4096
#define DIN   1024
#define DH    2048
#define K_TOT 3072      // DIN + DH
#define N_TOT 8192      // 4 * DH

// GEMM tile (256^2, m201-style 8-phase / 2-K-tile schedule)
#define BM 256
#define BN 256          // = 64 hidden units * 4 gates, gate-blocked @64 per ntile
#define BK 64
#define NK (K_TOT / BK) // 48 (even -> clean x2 unroll)

typedef _Float16 half8 __attribute__((ext_vector_type(8)));
typedef float   float4v __attribute__((ext_vector_type(4)));

// ---------- async global->LDS (16B per lane, wave-uniform LDS base) ----------
__device__ __forceinline__ void load_lds16(const void* g, void* l) {
    __builtin_amdgcn_global_load_lds(
        (const __attribute__((address_space(1))) void*)g,
        (__attribute__((address_space(3))) void*)l,
        16, 0, 0);
}

// ---------- fused cast kernel: A-part + W-part in one launch ----------
// blockIdx.x < A_BLOCKS: cast x|h_prev -> A [B_SZ, K_TOT] fp16
// else:                  cast W|R -> Wb [N_TOT, K_TOT] fp16, gate-blocked @64:
//   Wb row n: ntile = n>>8; gate g = (n>>6)&3; unit j = (n>>8)*64 + (n&63)
#define A_BLOCKS ((B_SZ * K_TOT / 8) / 256)
#define W_BLOCKS ((N_TOT * K_TOT / 8) / 256)

__global__ __launch_bounds__(256) void cast_all_kernel(
        const float* __restrict__ x, const float* __restrict__ h,
        const float* __restrict__ Wz, const float* __restrict__ Wi,
        const float* __restrict__ Wf, const float* __restrict__ Wo,
        const float* __restrict__ Rz, const float* __restrict__ Ri,
        const float* __restrict__ Rf, const float* __restrict__ Ro,
        _Float16* __restrict__ A, _Float16* __restrict__ Wb) {
    const float* src;
    _Float16* dst;
    if (blockIdx.x < A_BLOCKS) {
        int idx = (blockIdx.x * 256 + threadIdx.x) * 8;
        int b = idx / K_TOT;
        int c = idx - b * K_TOT;
        src = (c < DIN) ? (x + (size_t)b * DIN + c) : (h + (size_t)b * DH + (c - DIN));
        dst = A + idx;
    } else {
        int idx = ((blockIdx.x - A_BLOCKS) * 256 + threadIdx.x) * 8;
        int n = idx / K_TOT;
        int c = idx - n * K_TOT;
        int g = (n >> 6) & 3;
        int j = ((n >> 8) << 6) | (n & 63);
        const float* W = (g == 0) ? Wz : (g == 1) ? Wi : (g == 2) ? Wf : Wo;
        const float* R = (g == 0) ? Rz : (g == 1) ? Ri : (g == 2) ? Rf : Ro;
        src = (c < DIN) ? (W + (size_t)j * DIN + c) : (R + (size_t)j * DH + (c - DIN));
        dst = Wb + idx;
    }
    float4 v0 = *reinterpret_cast<const float4*>(src);
    float4 v1 = *reinterpret_cast<const float4*>(src + 4);
    half8 o;
    o[0] = (_Float16)v0.x; o[1] = (_Float16)v0.y;
    o[2] = (_Float16)v0.z; o[3] = (_Float16)v0.w;
    o[4] = (_Float16)v1.x; o[5] = (_Float16)v1.y;
    o[6] = (_Float16)v1.z; o[7] = (_Float16)v1.w;
    *reinterpret_cast<half8*>(dst) = o;
}

// ---------- fused GEMM + sLSTM pointwise epilogue -------------------------
// m201 8-phase template, 2 K-tiles per iteration, STATIC buffer objects.
// 512 threads = 8 waves (wm=wv>>2, wn=wv&3). Frag mapping:
//   A row = mf*32 + wm*16 + l16 (mf 0..7), B col = nf*64 + wn*16 + l16
//   (nf 0..3 = GATE). mf<4 -> A-lo, mf>=4 -> A-hi; nf<2 -> B-lo, nf>=2 -> B-hi.
// Per K-tile, 4 phases (C-quadrant x K=64, 16 MFMA each):
//   P1 (Alo,Blo): reads Alo-sub(8) + Blo-sub(4); stages A-hi(t+1)
//   P2 (Alo,Bhi): reads Bhi-sub(4);              stages A-lo(t+2)
//   P3 (Ahi,Bhi): reads Ahi-sub(8);              stages B-lo(t+2)
//   P4 (Ahi,Blo): register-only;                 stages B-hi(t+2); vmcnt(6)
// Each phase: {ds-reads; 1 half-tile stage} | s_barrier | lgkmcnt(0) |
//   setprio(1) 16xMFMA setprio(0) | s_barrier.
// vmcnt(6) ONCE per tile: at P4 there are 14 loads outstanding; landing to 6
// completes the ENTIRE next tile, leaving 3 half-tiles (t+2) in flight.
// Every ds_read's source object never has a pending DMA at that point
// (static objects -> AA proves it -> no compiler vmcnt(0) drains).
//
// LDS swizzle (64-elem = 128B rows): slot s of row r holds source chunk
// s^(r&7); staged via pre-swizzled global source (lane-constant), read with
// slot (kp*4+quad)^(l16&7). Bank-conflict-free (measured 0).
__global__ __launch_bounds__(512, 2) void slstm_gemm_kernel(
        const _Float16* __restrict__ A, const _Float16* __restrict__ Wb,
        const float* __restrict__ c_prev, const float* __restrict__ n_prev,
        const float* __restrict__ bz, const float* __restrict__ bi,
        const float* __restrict__ bf, const float* __restrict__ bo,
        float* __restrict__ Hout) {
    // 8 statically-disjoint half-tile buffers, 16 KB each = 128 KB total.
    __shared__ __align__(16) _Float16 As0lo[128 * BK], As0hi[128 * BK];
    __shared__ __align__(16) _Float16 As1lo[128 * BK], As1hi[128 * BK];
    __shared__ __align__(16) _Float16 Bs0lo[128 * BK], Bs0hi[128 * BK];
    __shared__ __align__(16) _Float16 Bs1lo[128 * BK], Bs1hi[128 * BK];

    // XCD-aware swizzle: 512 blocks, 8 XCDs -> XCD x owns mtiles {2x,2x+1}.
    const int bid   = blockIdx.x;                 // 0..511
    const int swz   = (bid & 7) * 64 + (bid >> 3);
    const int ntile = swz & 31;                   // 0..31
    const int mtile = swz >> 5;                   // 0..15
    const int m0 = mtile * BM;
    const int n0 = ntile * BN;

    const int tid  = threadIdx.x;
    const int wv   = tid >> 6;         // 0..7
    const int wm   = wv >> 2;          // 0..1
    const int wn   = wv & 3;           // 0..3
    const int l    = tid & 63;
    const int quad = l >> 4;
    const int l16  = l & 15;

    float4v acc[8][4];
#pragma unroll
    for (int i = 0; i < 8; i++)
#pragma unroll
        for (int j = 0; j < 4; j++) acc[i][j] = (float4v){0.f, 0.f, 0.f, 0.f};

    // ---- staging addressing (pre-swizzled global source) ----
    const int lrow  = l >> 3;                      // 0..7
    const int skoff = ((l & 7) ^ lrow) * 8;        // swizzled src k-chunk
    const _Float16* Ag0 = A  + (size_t)(m0 + wv * 16 + lrow) * K_TOT + skoff;        // A rows 0-127
    const _Float16* Ag1 = A  + (size_t)(m0 + 128 + wv * 16 + lrow) * K_TOT + skoff;  // A rows 128-255
    const _Float16* Bg0 = Wb + (size_t)(n0 + wv * 16 + lrow) * K_TOT + skoff;
    const _Float16* Bg1 = Wb + (size_t)(n0 + 128 + wv * 16 + lrow) * K_TOT + skoff;
    const int ldsA = wv * 1024;                    // wave-uniform elem offset

    // one half-tile = 2 x (64 lanes x 16B): rows wv*16+{0..7} and {8..15}
#define STAGE(ARR, G, kk) do { \
    load_lds16((G) + (kk),                     &ARR[ldsA]); \
    load_lds16((G) + (size_t)8 * K_TOT + (kk), &ARR[ldsA + 512]); } while (0)

    // ---- fragment read addressing ----
    const int aRowBase = wm * 16 + l16;            // + mf*32, local to half
    const int bColBase = wn * 16 + l16;            // + nf*64, local to half
    const int sl0 = ((0 + quad) ^ (l16 & 7)) * 8;  // kp=0 swizzled slot
    const int sl1 = ((4 + quad) ^ (l16 & 7)) * 8;  // kp=1

    half8 afr[4][2], bfr0[2][2], bfr1[2][2];

#define LOAD_A8(ARR) \
    _Pragma("unroll") \
    for (int mf = 0; mf < 4; ++mf) { \
        const _Float16* p = ARR + (size_t)(aRowBase + mf * 32) * BK; \
        afr[mf][0] = *reinterpret_cast<const half8*>(p + sl0); \
        afr[mf][1] = *reinterpret_cast<const half8*>(p + sl1); \
    }
#define LOAD_B4(DST, ARR) \
    _Pragma("unroll") \
    for (int nf = 0; nf < 2; ++nf) { \
        const _Float16* p = ARR + (size_t)(bColBase + nf * 64) * BK; \
        DST[nf][0] = *reinterpret_cast<const half8*>(p + sl0); \
        DST[nf][1] = *reinterpret_cast<const half8*>(p + sl1); \
    }
#define MFMA16(MB, NB, BF) \
    _Pragma("unroll") \
    for (int kp = 0; kp < 2; ++kp) \
    _Pragma("unroll") \
    for (int mf = 0; mf < 4; ++mf) \
    _Pragma("unroll") \
    for (int nf = 0; nf < 2; ++nf) \
        acc[(MB) + mf][(NB) + nf] = __builtin_amdgcn_mfma_f32_16x16x32_f16( \
            afr[mf][kp], BF[nf][kp], acc[(MB) + mf][(NB) + nf], 0, 0, 0);

#define BARRIER() __builtin_amdgcn_s_barrier()
#define WAIT_LGKM0() asm volatile("s_waitcnt lgkmcnt(0)" ::: "memory")

    // ---- prologue: tile0 (4 halves) -> vmcnt(4) -> tile1 lo halves -> vmcnt(6)
    STAGE(As0lo, Ag0, 0);
    STAGE(Bs0lo, Bg0, 0);
    STAGE(Bs0hi, Bg1, 0);
    STAGE(As0hi, Ag1, 0);
    asm volatile("s_waitcnt vmcnt(4)" ::: "memory");   // A0,B0(t0) landed
    STAGE(As1lo, Ag0, BK);
    STAGE(Bs1lo, Bg0, BK);
    STAGE(Bs1hi, Bg1, BK);
    asm volatile("s_waitcnt vmcnt(6)" ::: "memory");   // all of t0 landed
    BARRIER();

    for (int kt = 0; kt < NK; kt += 2) {
        const int k1 = (kt + 1) * BK;                          // kt+1 <= NK-1 always
        const int k2 = (kt + 2 < NK ? kt + 2 : 0) * BK;        // dummy re-stage at tail
        const int k3 = (kt + 3 < NK ? kt + 3 : 0) * BK;

        // ================= tile kt (even, buf0) =================
        // P1 (Alo,Blo)
        LOAD_A8(As0lo);
        LOAD_B4(bfr0, Bs0lo);
        STAGE(As1hi, Ag1, k1);                 // A-hi(t+1)
        asm volatile("s_waitcnt lgkmcnt(8)" ::: "memory");
        BARRIER();
        WAIT_LGKM0();
        __builtin_amdgcn_s_setprio(1);
        MFMA16(0, 0, bfr0);
        __builtin_amdgcn_s_setprio(0);
        BARRIER();
        // P2 (Alo,Bhi)
        LOAD_B4(bfr1, Bs0hi);
        STAGE(As0lo, Ag0, k2);                 // A-lo(t+2)
        BARRIER();
        WAIT_LGKM0();
        __builtin_amdgcn_s_setprio(1);
        MFMA16(0, 2, bfr1);
        __builtin_amdgcn_s_setprio(0);
        BARRIER();
        // P3 (Ahi,Bhi)
        LOAD_A8(As0hi);
        STAGE(Bs0lo, Bg0, k2);                 // B-lo(t+2)
        BARRIER();
        WAIT_LGKM0();
        __builtin_amdgcn_s_setprio(1);
        MFMA16(4, 2, bfr1);
        __builtin_amdgcn_s_setprio(0);
        BARRIER();
        // P4 (Ahi,Blo) — register-only
        STAGE(Bs0hi, Bg1, k2);                 // B-hi(t+2)
        asm volatile("s_waitcnt vmcnt(6)" ::: "memory");  // tile t+1 fully landed
        BARRIER();
        __builtin_amdgcn_s_setprio(1);
        MFMA16(4, 0, bfr0);
        __builtin_amdgcn_s_setprio(0);
        BARRIER();

        // ================= tile kt+1 (odd, buf1) =================
        // P5 (Alo,Blo)
        LOAD_A8(As1lo);
        LOAD_B4(bfr0, Bs1lo);
        STAGE(As0hi, Ag1, k2);                 // A-hi(t+2)
        asm volatile("s_waitcnt lgkmcnt(8)" ::: "memory");
        BARRIER();
        WAIT_LGKM0();
        __builtin_amdgcn_s_setprio(1);
        MFMA16(0, 0, bfr0);
        __builtin_amdgcn_s_setprio(0);
        BARRIER();
        // P6 (Alo,Bhi)
        LOAD_B4(bfr1, Bs1hi);
        STAGE(As1lo, Ag0, k3);                 // A-lo(t+3)
        BARRIER();
        WAIT_LGKM0();
        __builtin_amdgcn_s_setprio(1);
        MFMA16(0, 2, bfr1);
        __builtin_amdgcn_s_setprio(0);
        BARRIER();
        // P7 (Ahi,Bhi)
        LOAD_A8(As1hi);
        STAGE(Bs1lo, Bg0, k3);                 // B-lo(t+3)
        BARRIER();
        WAIT_LGKM0();
        __builtin_amdgcn_s_setprio(1);
        MFMA16(4, 2, bfr1);
        __builtin_amdgcn_s_setprio(0);
        BARRIER();
        // P8 (Ahi,Blo) — register-only
        STAGE(Bs1hi, Bg1, k3);                 // B-hi(t+3)
        asm volatile("s_waitcnt vmcnt(6)" ::: "memory");  // tile t+2 fully landed
        BARRIER();
        __builtin_amdgcn_s_setprio(1);
        MFMA16(4, 0, bfr0);
        __builtin_amdgcn_s_setprio(0);
        BARRIER();
    }

    // ---- Epilogue: C/D layout col=l16 (unit), row=quad*4+reg; nf = gate ----
    const int j = ntile * 64 + wn * 16 + l16;   // hidden unit, uniform over nf/mf
    const float bzv = bz[j], biv = bi[j], bfv = bf[j], bov = bo[j];
#pragma unroll
    for (int mf = 0; mf < 8; ++mf) {
#pragma unroll
        for (int r = 0; r < 4; ++r) {
            const int row = m0 + mf * 32 + wm * 16 + quad * 4 + r;
            const size_t off = (size_t)row * DH + j;
            const float az  = acc[mf][0][r] + bzv;
            const float ai  = acc[mf][1][r] + biv;
            const float af_ = acc[mf][2][r] + bfv;
            const float ao  = acc[mf][3][r] + bov;
            // tanh via exp, sign-safe (e2 <= 1 always; no inf/inf)
            const float ax = fabsf(az);
            const float e2 = __expf(-2.0f * ax);
            float tz = __fdividef(1.0f - e2, 1.0f + e2);
            tz = (az >= 0.0f) ? tz : -tz;
            const float iv = __expf(ai);
            const float fv = __expf(af_);
            const float ov = __fdividef(1.0f, 1.0f + __expf(-ao));
            const float cc = fv * c_prev[off] + iv * tz;
            const float nn = fv * n_prev[off] + iv;
            Hout[off] = ov * __fdividef(cc, nn);
        }
    }
#undef STAGE
#undef LOAD_A8
#undef LOAD_B4
#undef MFMA16
#undef BARRIER
#undef WAIT_LGKM0
}

extern "C" void kernel_launch(void* const* d_in, const int* in_sizes, int n_in,
                              void* d_out, int out_size, void* d_ws, size_t ws_size,
                              hipStream_t stream) {
    const float* x      = (const float*)d_in[0];
    const float* h_prev = (const float*)d_in[1];
    const float* c_prev = (const float*)d_in[2];
    const float* n_prev = (const float*)d_in[3];
    const float* Wz = (const float*)d_in[4];
    const float* Wi = (const float*)d_in[5];
    const float* Wf = (const float*)d_in[6];
    const float* Wo = (const float*)d_in[7];
    const float* bz = (const float*)d_in[8];
    const float* bi = (const float*)d_in[9];
    const float* bf = (const float*)d_in[10];
    const float* bo = (const float*)d_in[11];
    const float* Rz = (const float*)d_in[12];
    const float* Ri = (const float*)d_in[13];
    const float* Rf = (const float*)d_in[14];
    const float* Ro = (const float*)d_in[15];

    _Float16* A  = (_Float16*)d_ws;                       // [B_SZ, K_TOT]
    _Float16* Wb = A + (size_t)B_SZ * K_TOT;              // [N_TOT, K_TOT]

    cast_all_kernel<<<A_BLOCKS + W_BLOCKS, 256, 0, stream>>>(
        x, h_prev, Wz, Wi, Wf, Wo, Rz, Ri, Rf, Ro, A, Wb);

    dim3 grid(N_TOT / BN * (B_SZ / BM));   // 32 * 16 = 512 blocks (1D, swizzled in-kernel)
    slstm_gemm_kernel<<<grid, 512, 0, stream>>>(
        A, Wb, c_prev, n_prev, bz, bi, bf, bo, (float*)d_out);
}

// Round 3
// 427.426 us; speedup vs baseline: 1.0616x; 1.0178x over previous
//
#include <hip/hip_runtime.h>
#include <hip/hip_fp16.h>

// Problem constants
#define B_SZ  4096
#define DIN   1024
#define DH    2048
#define K_TOT 3072      // DIN + DH
#define N_TOT 8192      // 4 * DH

// GEMM tile (256^2, m201-style 8-phase / 2-K-tile schedule)
#define BM 256
#define BN 256          // = 64 hidden units * 4 gates, gate-blocked @64 per ntile
#define BK 64
#define NK (K_TOT / BK) // 48 (even -> clean x2 unroll)

typedef _Float16 half8 __attribute__((ext_vector_type(8)));
typedef float   float4v __attribute__((ext_vector_type(4)));

// ---------- async global->LDS (16B per lane, wave-uniform LDS base) ----------
__device__ __forceinline__ void load_lds16(const void* g, void* l) {
    __builtin_amdgcn_global_load_lds(
        (const __attribute__((address_space(1))) void*)g,
        (__attribute__((address_space(3))) void*)l,
        16, 0, 0);
}

// ---------- fused cast kernel: A-part + W-part in one launch ----------
// blockIdx.x < A_BLOCKS: cast x|h_prev -> A [B_SZ, K_TOT] fp16
// else:                  cast W|R -> Wb [N_TOT, K_TOT] fp16, gate-blocked @64:
//   Wb row n: ntile = n>>8; gate g = (n>>6)&3; unit j = (n>>8)*64 + (n&63)
#define A_BLOCKS ((B_SZ * K_TOT / 8) / 256)
#define W_BLOCKS ((N_TOT * K_TOT / 8) / 256)

__global__ __launch_bounds__(256) void cast_all_kernel(
        const float* __restrict__ x, const float* __restrict__ h,
        const float* __restrict__ Wz, const float* __restrict__ Wi,
        const float* __restrict__ Wf, const float* __restrict__ Wo,
        const float* __restrict__ Rz, const float* __restrict__ Ri,
        const float* __restrict__ Rf, const float* __restrict__ Ro,
        _Float16* __restrict__ A, _Float16* __restrict__ Wb) {
    const float* src;
    _Float16* dst;
    if (blockIdx.x < A_BLOCKS) {
        int idx = (blockIdx.x * 256 + threadIdx.x) * 8;
        int b = idx / K_TOT;
        int c = idx - b * K_TOT;
        src = (c < DIN) ? (x + (size_t)b * DIN + c) : (h + (size_t)b * DH + (c - DIN));
        dst = A + idx;
    } else {
        int idx = ((blockIdx.x - A_BLOCKS) * 256 + threadIdx.x) * 8;
        int n = idx / K_TOT;
        int c = idx - n * K_TOT;
        int g = (n >> 6) & 3;
        int j = ((n >> 8) << 6) | (n & 63);
        const float* W = (g == 0) ? Wz : (g == 1) ? Wi : (g == 2) ? Wf : Wo;
        const float* R = (g == 0) ? Rz : (g == 1) ? Ri : (g == 2) ? Rf : Ro;
        src = (c < DIN) ? (W + (size_t)j * DIN + c) : (R + (size_t)j * DH + (c - DIN));
        dst = Wb + idx;
    }
    float4 v0 = *reinterpret_cast<const float4*>(src);
    float4 v1 = *reinterpret_cast<const float4*>(src + 4);
    half8 o;
    o[0] = (_Float16)v0.x; o[1] = (_Float16)v0.y;
    o[2] = (_Float16)v0.z; o[3] = (_Float16)v0.w;
    o[4] = (_Float16)v1.x; o[5] = (_Float16)v1.y;
    o[6] = (_Float16)v1.z; o[7] = (_Float16)v1.w;
    *reinterpret_cast<half8*>(dst) = o;
}

// ---------- fused GEMM + sLSTM pointwise epilogue -------------------------
// 8-phase / 2-K-tile schedule with PER-PHASE-DISJOINT fragment registers.
// 512 threads = 8 waves (wm=wv>>2, wn=wv&3). Frag mapping:
//   A row = mf*32 + wm*16 + l16 (mf 0..7), B col = nf*64 + wn*16 + l16
//   (nf 0..3 = GATE). mf<4 -> A-lo, mf>=4 -> A-hi; nf<2 -> B-lo, nf>=2 -> B-hi.
// Register sets: afrL/afrH (A-lo/A-hi), bfrL/bfrH (B-lo/B-hi) — DISJOINT.
// Quadrant order ALTERNATES by tile parity so every phase's ds_reads write
// registers disjoint from the previous phase's MFMA operands (WAR-free =>
// reads overlap the MFMA pipe drain at every boundary):
//   even tile: (L,L)(L,H)(H,H)(H,L)   loads: [aL,bL] [bH] [aH] []
//   odd  tile: (L,H)(L,L)(H,L)(H,H)   loads: [aL,bH] [bL] [aH] []
// Boundary check (operands_k vs writes_{k+1}): all 8 boundaries disjoint,
// including the odd->even tile wrap (aH,bH vs aL,bL).
// Staging sites unchanged: E:[As1hi@k1, As0lo@k2, Bs0lo@k2, Bs0hi@k2+vmcnt(6)]
//                          O:[As0hi@k2, As1lo@k3, Bs1lo@k3, Bs1hi@k3+vmcnt(6)]
// vmcnt(6): 14 loads in flight at each P4 -> retire 8 = exactly all of the
// next tile; 3 half-tiles stay in flight. Never vmcnt(0) in the loop.
//
// LDS swizzle (64-elem = 128B rows): slot s of row r holds source chunk
// s^(r&7); staged via pre-swizzled global source (lane-constant), read with
// slot (kp*4+quad)^(l16&7). Bank-conflict-free (measured 0).
__global__ __launch_bounds__(512, 2) void slstm_gemm_kernel(
        const _Float16* __restrict__ A, const _Float16* __restrict__ Wb,
        const float* __restrict__ c_prev, const float* __restrict__ n_prev,
        const float* __restrict__ bz, const float* __restrict__ bi,
        const float* __restrict__ bf, const float* __restrict__ bo,
        float* __restrict__ Hout) {
    // A arrays first (ds-read imm offsets < 64 KB), then B. 8 x 16 KB = 128 KB.
    __shared__ __align__(16) _Float16 As0lo[128 * BK], As0hi[128 * BK];
    __shared__ __align__(16) _Float16 As1lo[128 * BK], As1hi[128 * BK];
    __shared__ __align__(16) _Float16 Bs0lo[128 * BK], Bs0hi[128 * BK];
    __shared__ __align__(16) _Float16 Bs1lo[128 * BK], Bs1hi[128 * BK];

    // XCD-aware swizzle: 512 blocks, 8 XCDs -> XCD x owns mtiles {2x,2x+1}.
    const int bid   = blockIdx.x;                 // 0..511
    const int swz   = (bid & 7) * 64 + (bid >> 3);
    const int ntile = swz & 31;                   // 0..31
    const int mtile = swz >> 5;                   // 0..15
    const int m0 = mtile * BM;
    const int n0 = ntile * BN;

    const int tid  = threadIdx.x;
    const int wv   = tid >> 6;         // 0..7
    const int wm   = wv >> 2;          // 0..1
    const int wn   = wv & 3;           // 0..3
    const int l    = tid & 63;
    const int quad = l >> 4;
    const int l16  = l & 15;

    float4v acc[8][4];
#pragma unroll
    for (int i = 0; i < 8; i++)
#pragma unroll
        for (int j = 0; j < 4; j++) acc[i][j] = (float4v){0.f, 0.f, 0.f, 0.f};

    // ---- staging addressing (pre-swizzled global source) ----
    const int lrow  = l >> 3;                      // 0..7
    const int skoff = ((l & 7) ^ lrow) * 8;        // swizzled src k-chunk
    const _Float16* Ag0 = A  + (size_t)(m0 + wv * 16 + lrow) * K_TOT + skoff;        // A rows 0-127
    const _Float16* Ag1 = A  + (size_t)(m0 + 128 + wv * 16 + lrow) * K_TOT + skoff;  // A rows 128-255
    const _Float16* Bg0 = Wb + (size_t)(n0 + wv * 16 + lrow) * K_TOT + skoff;
    const _Float16* Bg1 = Wb + (size_t)(n0 + 128 + wv * 16 + lrow) * K_TOT + skoff;
    const int ldsA = wv * 1024;                    // wave-uniform elem offset

    // one half-tile = 2 x (64 lanes x 16B): rows wv*16+{0..7} and {8..15}
#define STAGE(ARR, G, kk) do { \
    load_lds16((G) + (kk),                     &ARR[ldsA]); \
    load_lds16((G) + (size_t)8 * K_TOT + (kk), &ARR[ldsA + 512]); } while (0)

    // ---- fragment read addressing ----
    const int aRowBase = wm * 16 + l16;            // + mf*32, local to half
    const int bColBase = wn * 16 + l16;            // + nf*64, local to half
    const int sl0 = ((0 + quad) ^ (l16 & 7)) * 8;  // kp=0 swizzled slot
    const int sl1 = ((4 + quad) ^ (l16 & 7)) * 8;  // kp=1

    // Per-phase-disjoint fragment register sets (96 VGPR total).
    half8 afrL[4][2], afrH[4][2], bfrL[2][2], bfrH[2][2];

#define LOAD_A8(DST, ARR) \
    _Pragma("unroll") \
    for (int mf = 0; mf < 4; ++mf) { \
        const _Float16* p = ARR + (size_t)(aRowBase + mf * 32) * BK; \
        DST[mf][0] = *reinterpret_cast<const half8*>(p + sl0); \
        DST[mf][1] = *reinterpret_cast<const half8*>(p + sl1); \
    }
#define LOAD_B4(DST, ARR) \
    _Pragma("unroll") \
    for (int nf = 0; nf < 2; ++nf) { \
        const _Float16* p = ARR + (size_t)(bColBase + nf * 64) * BK; \
        DST[nf][0] = *reinterpret_cast<const half8*>(p + sl0); \
        DST[nf][1] = *reinterpret_cast<const half8*>(p + sl1); \
    }
#define MFMA16(MB, NB, AF, BF) \
    _Pragma("unroll") \
    for (int kp = 0; kp < 2; ++kp) \
    _Pragma("unroll") \
    for (int mf = 0; mf < 4; ++mf) \
    _Pragma("unroll") \
    for (int nf = 0; nf < 2; ++nf) \
        acc[(MB) + mf][(NB) + nf] = __builtin_amdgcn_mfma_f32_16x16x32_f16( \
            AF[mf][kp], BF[nf][kp], acc[(MB) + mf][(NB) + nf], 0, 0, 0);

#define BARRIER()  __builtin_amdgcn_s_barrier()
#define SCHEDPIN() __builtin_amdgcn_sched_barrier(0)

    // ---- prologue: tile0 (4 halves) + tile1 lo-3 halves -> vmcnt(6) ----
    STAGE(As0lo, Ag0, 0);
    STAGE(Bs0lo, Bg0, 0);
    STAGE(Bs0hi, Bg1, 0);
    STAGE(As0hi, Ag1, 0);
    STAGE(As1lo, Ag0, BK);
    STAGE(Bs1lo, Bg0, BK);
    STAGE(Bs1hi, Bg1, BK);
    asm volatile("s_waitcnt vmcnt(6)");   // all of tile0 landed; 3 halves fly
    SCHEDPIN();
    BARRIER();

    for (int kt = 0; kt < NK; kt += 2) {
        const int k1 = (kt + 1) * BK;                          // kt+1 <= NK-1 always
        const int k2 = (kt + 2 < NK ? kt + 2 : 0) * BK;        // dummy re-stage at tail
        const int k3 = (kt + 3 < NK ? kt + 3 : 0) * BK;

        // ============ tile kt (EVEN, buf0): (L,L)(L,H)(H,H)(H,L) ============
        // E.P1 (Alo,Blo)
        LOAD_A8(afrL, As0lo);
        LOAD_B4(bfrL, Bs0lo);
        STAGE(As1hi, Ag1, k1);                 // A-hi(t+1)
        asm volatile("s_waitcnt lgkmcnt(8)");
        BARRIER();
        __builtin_amdgcn_s_setprio(1);
        MFMA16(0, 0, afrL, bfrL);
        __builtin_amdgcn_s_setprio(0);
        BARRIER();
        // E.P2 (Alo,Bhi)
        LOAD_B4(bfrH, Bs0hi);
        STAGE(As0lo, Ag0, k2);                 // A-lo(t+2)
        BARRIER();
        __builtin_amdgcn_s_setprio(1);
        MFMA16(0, 2, afrL, bfrH);
        __builtin_amdgcn_s_setprio(0);
        BARRIER();
        // E.P3 (Ahi,Bhi)
        LOAD_A8(afrH, As0hi);
        STAGE(Bs0lo, Bg0, k2);                 // B-lo(t+2)
        BARRIER();
        __builtin_amdgcn_s_setprio(1);
        MFMA16(4, 2, afrH, bfrH);
        __builtin_amdgcn_s_setprio(0);
        BARRIER();
        // E.P4 (Ahi,Blo) — register-only
        STAGE(Bs0hi, Bg1, k2);                 // B-hi(t+2)
        asm volatile("s_waitcnt vmcnt(6)");    // tile t+1 fully landed
        SCHEDPIN();
        BARRIER();
        __builtin_amdgcn_s_setprio(1);
        MFMA16(4, 0, afrH, bfrL);
        __builtin_amdgcn_s_setprio(0);
        BARRIER();

        // ============ tile kt+1 (ODD, buf1): (L,H)(L,L)(H,L)(H,H) ============
        // O.P1 (Alo,Bhi)
        LOAD_A8(afrL, As1lo);
        LOAD_B4(bfrH, Bs1hi);
        STAGE(As0hi, Ag1, k2);                 // A-hi(t+2)
        asm volatile("s_waitcnt lgkmcnt(8)");
        BARRIER();
        __builtin_amdgcn_s_setprio(1);
        MFMA16(0, 2, afrL, bfrH);
        __builtin_amdgcn_s_setprio(0);
        BARRIER();
        // O.P2 (Alo,Blo)
        LOAD_B4(bfrL, Bs1lo);
        STAGE(As1lo, Ag0, k3);                 // A-lo(t+3)
        BARRIER();
        __builtin_amdgcn_s_setprio(1);
        MFMA16(0, 0, afrL, bfrL);
        __builtin_amdgcn_s_setprio(0);
        BARRIER();
        // O.P3 (Ahi,Blo)
        LOAD_A8(afrH, As1hi);
        STAGE(Bs1lo, Bg0, k3);                 // B-lo(t+3)
        BARRIER();
        __builtin_amdgcn_s_setprio(1);
        MFMA16(4, 0, afrH, bfrL);
        __builtin_amdgcn_s_setprio(0);
        BARRIER();
        // O.P4 (Ahi,Bhi) — register-only
        STAGE(Bs1hi, Bg1, k3);                 // B-hi(t+3)
        asm volatile("s_waitcnt vmcnt(6)");    // tile t+2 fully landed
        SCHEDPIN();
        BARRIER();
        __builtin_amdgcn_s_setprio(1);
        MFMA16(4, 2, afrH, bfrH);
        __builtin_amdgcn_s_setprio(0);
        BARRIER();
    }

    // ---- Epilogue: C/D layout col=l16 (unit), row=quad*4+reg; nf = gate ----
    const int j = ntile * 64 + wn * 16 + l16;   // hidden unit, uniform over nf/mf
    const float bzv = bz[j], biv = bi[j], bfv = bf[j], bov = bo[j];
#pragma unroll
    for (int mf = 0; mf < 8; ++mf) {
#pragma unroll
        for (int r = 0; r < 4; ++r) {
            const int row = m0 + mf * 32 + wm * 16 + quad * 4 + r;
            const size_t off = (size_t)row * DH + j;
            const float az  = acc[mf][0][r] + bzv;
            const float ai  = acc[mf][1][r] + biv;
            const float af_ = acc[mf][2][r] + bfv;
            const float ao  = acc[mf][3][r] + bov;
            // tanh via exp, sign-safe (e2 <= 1 always; no inf/inf)
            const float ax = fabsf(az);
            const float e2 = __expf(-2.0f * ax);
            float tz = __fdividef(1.0f - e2, 1.0f + e2);
            tz = (az >= 0.0f) ? tz : -tz;
            const float iv = __expf(ai);
            const float fv = __expf(af_);
            const float ov = __fdividef(1.0f, 1.0f + __expf(-ao));
            const float cc = fv * c_prev[off] + iv * tz;
            const float nn = fv * n_prev[off] + iv;
            Hout[off] = ov * __fdividef(cc, nn);
        }
    }
#undef STAGE
#undef LOAD_A8
#undef LOAD_B4
#undef MFMA16
#undef BARRIER
#undef SCHEDPIN
}

extern "C" void kernel_launch(void* const* d_in, const int* in_sizes, int n_in,
                              void* d_out, int out_size, void* d_ws, size_t ws_size,
                              hipStream_t stream) {
    const float* x      = (const float*)d_in[0];
    const float* h_prev = (const float*)d_in[1];
    const float* c_prev = (const float*)d_in[2];
    const float* n_prev = (const float*)d_in[3];
    const float* Wz = (const float*)d_in[4];
    const float* Wi = (const float*)d_in[5];
    const float* Wf = (const float*)d_in[6];
    const float* Wo = (const float*)d_in[7];
    const float* bz = (const float*)d_in[8];
    const float* bi = (const float*)d_in[9];
    const float* bf = (const float*)d_in[10];
    const float* bo = (const float*)d_in[11];
    const float* Rz = (const float*)d_in[12];
    const float* Ri = (const float*)d_in[13];
    const float* Rf = (const float*)d_in[14];
    const float* Ro = (const float*)d_in[15];

    _Float16* A  = (_Float16*)d_ws;                       // [B_SZ, K_TOT]
    _Float16* Wb = A + (size_t)B_SZ * K_TOT;              // [N_TOT, K_TOT]

    cast_all_kernel<<<A_BLOCKS + W_BLOCKS, 256, 0, stream>>>(
        x, h_prev, Wz, Wi, Wf, Wo, Rz, Ri, Rf, Ro, A, Wb);

    dim3 grid(N_TOT / BN * (B_SZ / BM));   // 32 * 16 = 512 blocks (1D, swizzled in-kernel)
    slstm_gemm_kernel<<<grid, 512, 0, stream>>>(
        A, Wb, c_prev, n_prev, bz, bi, bf, bo, (float*)d_out);
}

// Round 4
// 421.191 us; speedup vs baseline: 1.0773x; 1.0148x over previous
//
#include <hip/hip_runtime.h>
#include <hip/hip_fp16.h>

// Problem constants
#define B_SZ  4096
#define DIN   1024
#define DH    2048
#define K_TOT 3072      // DIN + DH
#define N_TOT 8192      // 4 * DH

// GEMM tile (256^2, 8-phase / 2-K-tile schedule, thinned barriers)
#define BM 256
#define BN 256          // = 64 hidden units * 4 gates, gate-blocked @64 per ntile
#define BK 64
#define NK (K_TOT / BK) // 48 (even -> clean x2 unroll)

typedef _Float16 half8 __attribute__((ext_vector_type(8)));
typedef float   float4v __attribute__((ext_vector_type(4)));

// ---------- async global->LDS (16B per lane, wave-uniform LDS base) ----------
__device__ __forceinline__ void load_lds16(const void* g, void* l) {
    __builtin_amdgcn_global_load_lds(
        (const __attribute__((address_space(1))) void*)g,
        (__attribute__((address_space(3))) void*)l,
        16, 0, 0);
}

// ---------- fused cast kernel: A-part + W-part, grid-strided ----------
// chunk ch < A_CHUNKS: cast x|h_prev -> A [B_SZ, K_TOT] fp16
// else:                cast W|R -> Wb [N_TOT, K_TOT] fp16, gate-blocked @64:
//   Wb row n: ntile = n>>8; gate g = (n>>6)&3; unit j = (n>>8)*64 + (n&63)
// 2048 blocks x 256 threads, 9 grid-stride iterations (diagnostic: was 18432
// tiny blocks; if the ~200us total-minus-GEMM gap was dispatch-bound, this
// collapses it; if it's harness tax, no change).
#define A_CHUNKS     (B_SZ * K_TOT / 8)
#define TOTAL_CHUNKS ((B_SZ + N_TOT) * K_TOT / 8)
#define CAST_BLOCKS  2048

__global__ __launch_bounds__(256) void cast_all_kernel(
        const float* __restrict__ x, const float* __restrict__ h,
        const float* __restrict__ Wz, const float* __restrict__ Wi,
        const float* __restrict__ Wf, const float* __restrict__ Wo,
        const float* __restrict__ Rz, const float* __restrict__ Ri,
        const float* __restrict__ Rf, const float* __restrict__ Ro,
        _Float16* __restrict__ A, _Float16* __restrict__ Wb) {
    for (int ch = blockIdx.x * 256 + threadIdx.x; ch < TOTAL_CHUNKS;
         ch += CAST_BLOCKS * 256) {
        const float* src;
        _Float16* dst;
        if (ch < A_CHUNKS) {
            int idx = ch * 8;
            int b = idx / K_TOT;
            int c = idx - b * K_TOT;
            src = (c < DIN) ? (x + (size_t)b * DIN + c) : (h + (size_t)b * DH + (c - DIN));
            dst = A + idx;
        } else {
            int idx = (ch - A_CHUNKS) * 8;
            int n = idx / K_TOT;
            int c = idx - n * K_TOT;
            int g = (n >> 6) & 3;
            int j = ((n >> 8) << 6) | (n & 63);
            const float* W = (g == 0) ? Wz : (g == 1) ? Wi : (g == 2) ? Wf : Wo;
            const float* R = (g == 0) ? Rz : (g == 1) ? Ri : (g == 2) ? Rf : Ro;
            src = (c < DIN) ? (W + (size_t)j * DIN + c) : (R + (size_t)j * DH + (c - DIN));
            dst = Wb + idx;
        }
        float4 v0 = *reinterpret_cast<const float4*>(src);
        float4 v1 = *reinterpret_cast<const float4*>(src + 4);
        half8 o;
        o[0] = (_Float16)v0.x; o[1] = (_Float16)v0.y;
        o[2] = (_Float16)v0.z; o[3] = (_Float16)v0.w;
        o[4] = (_Float16)v1.x; o[5] = (_Float16)v1.y;
        o[6] = (_Float16)v1.z; o[7] = (_Float16)v1.w;
        *reinterpret_cast<half8*>(dst) = o;
    }
}

// ---------- fused GEMM + sLSTM pointwise epilogue -------------------------
// 8-phase / 2-K-tile schedule, PER-PHASE-DISJOINT fragment registers,
// THINNED BARRIERS: 6 per 2 K-tiles (was 16). Each kept barrier maps to a
// required hazard: "all waves' last read of LDS buffer X" must precede "any
// wave's re-stage of X". Derivation per stage-site (stage > kept-barrier >
// all reads):
//   E.P2 stages As0lo : reads in E.P1  -> BAR1 (post-E.P1-reads)
//   E.P3 stages Bs0lo : reads in E.P1  -> BAR1
//   E.P4 stages Bs0hi : reads in E.P2  -> BAR2 (in E.P3, pre-MFMA)
//   O.P1 stages As0hi : reads in E.P3  -> BAR3 (E.P4 vmcnt barrier)
//   O.P2 stages As1lo : reads in O.P1  -> BAR4 (post-O.P1-reads)
//   O.P3 stages Bs1lo : reads in O.P2  -> BAR5 (post-O.P2-reads)
//   O.P4 stages Bs1hi : reads in O.P1  -> BAR4
//   E.P1' stages As1hi: reads in O.P3  -> BAR6 (O.P4 vmcnt barrier)
// All other barriers removed -> waves skew up to a phase: one wave's ds_reads
// overlap another's MFMA cluster (the overlap the lockstep structure forbade;
// setprio now has real arbitration work). Register WAR across unbarriered
// phases is safe: afrL/afrH/bfrL/bfrH disjoint + parity-alternating quadrant
// order (even (L,L)(L,H)(H,H)(H,L), odd (L,H)(L,L)(H,L)(H,H)).
// vmcnt(6) once per tile at P4: 14 outstanding -> retire oldest 8 = exactly
// the whole next tile; 3 half-tiles stay in flight. Never vmcnt(0) in loop.
//
// LDS swizzle (64-elem = 128B rows): slot s of row r holds source chunk
// s^(r&7); staged via pre-swizzled global source (lane-constant), read with
// slot (kp*4+quad)^(l16&7). Bank-conflict-free (measured 0).
__global__ __launch_bounds__(512, 2) void slstm_gemm_kernel(
        const _Float16* __restrict__ A, const _Float16* __restrict__ Wb,
        const float* __restrict__ c_prev, const float* __restrict__ n_prev,
        const float* __restrict__ bz, const float* __restrict__ bi,
        const float* __restrict__ bf, const float* __restrict__ bo,
        float* __restrict__ Hout) {
    // A arrays first (ds-read imm offsets < 64 KB), then B. 8 x 16 KB = 128 KB.
    __shared__ __align__(16) _Float16 As0lo[128 * BK], As0hi[128 * BK];
    __shared__ __align__(16) _Float16 As1lo[128 * BK], As1hi[128 * BK];
    __shared__ __align__(16) _Float16 Bs0lo[128 * BK], Bs0hi[128 * BK];
    __shared__ __align__(16) _Float16 Bs1lo[128 * BK], Bs1hi[128 * BK];

    // XCD-aware swizzle: 512 blocks, 8 XCDs -> XCD x owns mtiles {2x,2x+1}.
    const int bid   = blockIdx.x;                 // 0..511
    const int swz   = (bid & 7) * 64 + (bid >> 3);
    const int ntile = swz & 31;                   // 0..31
    const int mtile = swz >> 5;                   // 0..15
    const int m0 = mtile * BM;
    const int n0 = ntile * BN;

    const int tid  = threadIdx.x;
    const int wv   = tid >> 6;         // 0..7
    const int wm   = wv >> 2;          // 0..1
    const int wn   = wv & 3;           // 0..3
    const int l    = tid & 63;
    const int quad = l >> 4;
    const int l16  = l & 15;

    float4v acc[8][4];
#pragma unroll
    for (int i = 0; i < 8; i++)
#pragma unroll
        for (int j = 0; j < 4; j++) acc[i][j] = (float4v){0.f, 0.f, 0.f, 0.f};

    // ---- staging addressing (pre-swizzled global source) ----
    const int lrow  = l >> 3;                      // 0..7
    const int skoff = ((l & 7) ^ lrow) * 8;        // swizzled src k-chunk
    const _Float16* Ag0 = A  + (size_t)(m0 + wv * 16 + lrow) * K_TOT + skoff;        // A rows 0-127
    const _Float16* Ag1 = A  + (size_t)(m0 + 128 + wv * 16 + lrow) * K_TOT + skoff;  // A rows 128-255
    const _Float16* Bg0 = Wb + (size_t)(n0 + wv * 16 + lrow) * K_TOT + skoff;
    const _Float16* Bg1 = Wb + (size_t)(n0 + 128 + wv * 16 + lrow) * K_TOT + skoff;
    const int ldsA = wv * 1024;                    // wave-uniform elem offset

    // one half-tile = 2 x (64 lanes x 16B): rows wv*16+{0..7} and {8..15}
#define STAGE(ARR, G, kk) do { \
    load_lds16((G) + (kk),                     &ARR[ldsA]); \
    load_lds16((G) + (size_t)8 * K_TOT + (kk), &ARR[ldsA + 512]); } while (0)

    // ---- fragment read addressing ----
    const int aRowBase = wm * 16 + l16;            // + mf*32, local to half
    const int bColBase = wn * 16 + l16;            // + nf*64, local to half
    const int sl0 = ((0 + quad) ^ (l16 & 7)) * 8;  // kp=0 swizzled slot
    const int sl1 = ((4 + quad) ^ (l16 & 7)) * 8;  // kp=1

    // Per-phase-disjoint fragment register sets (96 VGPR total).
    half8 afrL[4][2], afrH[4][2], bfrL[2][2], bfrH[2][2];

#define LOAD_A8(DST, ARR) \
    _Pragma("unroll") \
    for (int mf = 0; mf < 4; ++mf) { \
        const _Float16* p = ARR + (size_t)(aRowBase + mf * 32) * BK; \
        DST[mf][0] = *reinterpret_cast<const half8*>(p + sl0); \
        DST[mf][1] = *reinterpret_cast<const half8*>(p + sl1); \
    }
#define LOAD_B4(DST, ARR) \
    _Pragma("unroll") \
    for (int nf = 0; nf < 2; ++nf) { \
        const _Float16* p = ARR + (size_t)(bColBase + nf * 64) * BK; \
        DST[nf][0] = *reinterpret_cast<const half8*>(p + sl0); \
        DST[nf][1] = *reinterpret_cast<const half8*>(p + sl1); \
    }
#define MFMA16(MB, NB, AF, BF) \
    _Pragma("unroll") \
    for (int kp = 0; kp < 2; ++kp) \
    _Pragma("unroll") \
    for (int mf = 0; mf < 4; ++mf) \
    _Pragma("unroll") \
    for (int nf = 0; nf < 2; ++nf) \
        acc[(MB) + mf][(NB) + nf] = __builtin_amdgcn_mfma_f32_16x16x32_f16( \
            AF[mf][kp], BF[nf][kp], acc[(MB) + mf][(NB) + nf], 0, 0, 0);

#define BARRIER()  __builtin_amdgcn_s_barrier()
#define SCHEDPIN() __builtin_amdgcn_sched_barrier(0)

    // ---- prologue: tile0 (4 halves) + tile1 lo-3 halves -> vmcnt(6) ----
    STAGE(As0lo, Ag0, 0);
    STAGE(Bs0lo, Bg0, 0);
    STAGE(Bs0hi, Bg1, 0);
    STAGE(As0hi, Ag1, 0);
    STAGE(As1lo, Ag0, BK);
    STAGE(Bs1lo, Bg0, BK);
    STAGE(Bs1hi, Bg1, BK);
    asm volatile("s_waitcnt vmcnt(6)");   // all of tile0 landed; 3 halves fly
    SCHEDPIN();
    BARRIER();

    for (int kt = 0; kt < NK; kt += 2) {
        const int k1 = (kt + 1) * BK;                          // kt+1 <= NK-1 always
        const int k2 = (kt + 2 < NK ? kt + 2 : 0) * BK;        // dummy re-stage at tail
        const int k3 = (kt + 3 < NK ? kt + 3 : 0) * BK;

        // ============ tile kt (EVEN, buf0): (L,L)(L,H)(H,H)(H,L) ============
        // E.P1 (Alo,Blo)
        LOAD_A8(afrL, As0lo);
        LOAD_B4(bfrL, Bs0lo);
        STAGE(As1hi, Ag1, k1);                 // A-hi(t+1)
        asm volatile("s_waitcnt lgkmcnt(8)");
        BARRIER();                             // BAR1: E.P1 reads done (As0lo,Bs0lo)
        __builtin_amdgcn_s_setprio(1);
        MFMA16(0, 0, afrL, bfrL);
        __builtin_amdgcn_s_setprio(0);
        // E.P2 (Alo,Bhi) — no barriers
        LOAD_B4(bfrH, Bs0hi);
        STAGE(As0lo, Ag0, k2);                 // A-lo(t+2)   [safe: BAR1]
        __builtin_amdgcn_s_setprio(1);
        MFMA16(0, 2, afrL, bfrH);
        __builtin_amdgcn_s_setprio(0);
        // E.P3 (Ahi,Bhi)
        LOAD_A8(afrH, As0hi);
        STAGE(Bs0lo, Bg0, k2);                 // B-lo(t+2)   [safe: BAR1]
        BARRIER();                             // BAR2: E.P2 reads done (Bs0hi)
        __builtin_amdgcn_s_setprio(1);
        MFMA16(4, 2, afrH, bfrH);
        __builtin_amdgcn_s_setprio(0);
        // E.P4 (Ahi,Blo) — register-only
        STAGE(Bs0hi, Bg1, k2);                 // B-hi(t+2)   [safe: BAR2]
        asm volatile("s_waitcnt vmcnt(6)");    // tile t+1 fully landed
        SCHEDPIN();
        BARRIER();                             // BAR3: vmcnt rendezvous + E.P3 reads done
        __builtin_amdgcn_s_setprio(1);
        MFMA16(4, 0, afrH, bfrL);
        __builtin_amdgcn_s_setprio(0);

        // ============ tile kt+1 (ODD, buf1): (L,H)(L,L)(H,L)(H,H) ============
        // O.P1 (Alo,Bhi)
        LOAD_A8(afrL, As1lo);
        LOAD_B4(bfrH, Bs1hi);
        STAGE(As0hi, Ag1, k2);                 // A-hi(t+2)   [safe: BAR3]
        asm volatile("s_waitcnt lgkmcnt(8)");
        BARRIER();                             // BAR4: O.P1 reads done (As1lo,Bs1hi)
        __builtin_amdgcn_s_setprio(1);
        MFMA16(0, 2, afrL, bfrH);
        __builtin_amdgcn_s_setprio(0);
        // O.P2 (Alo,Blo)
        LOAD_B4(bfrL, Bs1lo);
        STAGE(As1lo, Ag0, k3);                 // A-lo(t+3)   [safe: BAR4]
        BARRIER();                             // BAR5: O.P2 reads done (Bs1lo)
        __builtin_amdgcn_s_setprio(1);
        MFMA16(0, 0, afrL, bfrL);
        __builtin_amdgcn_s_setprio(0);
        // O.P3 (Ahi,Blo) — no barriers
        LOAD_A8(afrH, As1hi);
        STAGE(Bs1lo, Bg0, k3);                 // B-lo(t+3)   [safe: BAR5]
        __builtin_amdgcn_s_setprio(1);
        MFMA16(4, 0, afrH, bfrL);
        __builtin_amdgcn_s_setprio(0);
        // O.P4 (Ahi,Bhi) — register-only
        STAGE(Bs1hi, Bg1, k3);                 // B-hi(t+3)   [safe: BAR4]
        asm volatile("s_waitcnt vmcnt(6)");    // tile t+2 fully landed
        SCHEDPIN();
        BARRIER();                             // BAR6: vmcnt rendezvous + O.P3 reads done
        __builtin_amdgcn_s_setprio(1);
        MFMA16(4, 2, afrH, bfrH);
        __builtin_amdgcn_s_setprio(0);
    }

    // ---- Epilogue: C/D layout col=l16 (unit), row=quad*4+reg; nf = gate ----
    const int j = ntile * 64 + wn * 16 + l16;   // hidden unit, uniform over nf/mf
    const float bzv = bz[j], biv = bi[j], bfv = bf[j], bov = bo[j];
#pragma unroll
    for (int mf = 0; mf < 8; ++mf) {
#pragma unroll
        for (int r = 0; r < 4; ++r) {
            const int row = m0 + mf * 32 + wm * 16 + quad * 4 + r;
            const size_t off = (size_t)row * DH + j;
            const float az  = acc[mf][0][r] + bzv;
            const float ai  = acc[mf][1][r] + biv;
            const float af_ = acc[mf][2][r] + bfv;
            const float ao  = acc[mf][3][r] + bov;
            // tanh via exp, sign-safe (e2 <= 1 always; no inf/inf)
            const float ax = fabsf(az);
            const float e2 = __expf(-2.0f * ax);
            float tz = __fdividef(1.0f - e2, 1.0f + e2);
            tz = (az >= 0.0f) ? tz : -tz;
            const float iv = __expf(ai);
            const float fv = __expf(af_);
            const float ov = __fdividef(1.0f, 1.0f + __expf(-ao));
            const float cc = fv * c_prev[off] + iv * tz;
            const float nn = fv * n_prev[off] + iv;
            Hout[off] = ov * __fdividef(cc, nn);
        }
    }
#undef STAGE
#undef LOAD_A8
#undef LOAD_B4
#undef MFMA16
#undef BARRIER
#undef SCHEDPIN
}

extern "C" void kernel_launch(void* const* d_in, const int* in_sizes, int n_in,
                              void* d_out, int out_size, void* d_ws, size_t ws_size,
                              hipStream_t stream) {
    const float* x      = (const float*)d_in[0];
    const float* h_prev = (const float*)d_in[1];
    const float* c_prev = (const float*)d_in[2];
    const float* n_prev = (const float*)d_in[3];
    const float* Wz = (const float*)d_in[4];
    const float* Wi = (const float*)d_in[5];
    const float* Wf = (const float*)d_in[6];
    const float* Wo = (const float*)d_in[7];
    const float* bz = (const float*)d_in[8];
    const float* bi = (const float*)d_in[9];
    const float* bf = (const float*)d_in[10];
    const float* bo = (const float*)d_in[11];
    const float* Rz = (const float*)d_in[12];
    const float* Ri = (const float*)d_in[13];
    const float* Rf = (const float*)d_in[14];
    const float* Ro = (const float*)d_in[15];

    _Float16* A  = (_Float16*)d_ws;                       // [B_SZ, K_TOT]
    _Float16* Wb = A + (size_t)B_SZ * K_TOT;              // [N_TOT, K_TOT]

    cast_all_kernel<<<CAST_BLOCKS, 256, 0, stream>>>(
        x, h_prev, Wz, Wi, Wf, Wo, Rz, Ri, Rf, Ro, A, Wb);

    dim3 grid(N_TOT / BN * (B_SZ / BM));   // 32 * 16 = 512 blocks (1D, swizzled in-kernel)
    slstm_gemm_kernel<<<grid, 512, 0, stream>>>(
        A, Wb, c_prev, n_prev, bz, bi, bf, bo, (float*)d_out);
}